// Round 1
// baseline (1654.946 us; speedup 1.0000x reference)
//
#include <hip/hip_runtime.h>
#include <cstddef>

#define NN 100000
#define DD 128
#define ND (NN * DD)
#define BN_EPS 1e-5f

// ws float layout:
//   [0, ND)               agg (zeroed)
//   [ND, ND+NN)           deg (zeroed)
//   [ND+NN, +128)         colsum (zeroed)
//   [ND+NN+128, +128)     colsumsq (zeroed)
//   ND+NN+256             int64-flag (int slot, zeroed)
//   [ND+NN+320, +NN)      dinv
//   [ND+2*NN+320, +ND)    h
// memset range: first ND+NN+320 floats

__global__ void k_detect(const int* __restrict__ ei, int* __restrict__ flag) {
    // If edge_index is stored as int64, the high 32-bit word of every entry is 0
    // (values are in [0, 100000)). If int32, "high words" are random node ids:
    // P(all 64 == 0) ~ 0.
    if (threadIdx.x == 0) {
        int allz = 1;
        for (int i = 0; i < 64; ++i)
            if (ei[2 * i + 1] != 0) { allz = 0; break; }
        *flag = allz;
    }
}

__global__ void k_deg(const int* __restrict__ ei, const int* __restrict__ flag,
                      float* __restrict__ deg, int E) {
    int e = blockIdx.x * 256 + threadIdx.x;
    if (e >= E) return;
    int f = *flag;
    int c = f ? ei[2 * (E + e)] : ei[E + e];
    atomicAdd(&deg[c], 1.0f);
}

__global__ void k_dinv(const float* __restrict__ deg, float* __restrict__ dinv) {
    int i = blockIdx.x * 256 + threadIdx.x;
    if (i < NN) {
        float d = deg[i];
        dinv[i] = d > 0.f ? rsqrtf(fmaxf(d, 1.f)) : 0.f;
    }
}

// h = x @ W^T   (x: [NN,128], W: [128,128] row-major [out][in])
// Block: 256 threads, 16 rows per block. Thread t: o = t&127, rg = t>>7 (8 rows each).
// W staged transposed in LDS in two 64-k chunks (sW[k][o], pad 129) -> conflict-free
// broadcast-free column reads; x tile broadcast from LDS.
__global__ __launch_bounds__(256) void k_gemm(const float* __restrict__ x,
                                              const float* __restrict__ W,
                                              float* __restrict__ h) {
    __shared__ float sX[16][128];        // 8 KB
    __shared__ float sW[64][129];        // ~33 KB
    int t = threadIdx.x;
    int o = t & 127;
    int rg = t >> 7;
    size_t base_row = (size_t)blockIdx.x * 16;

    const float4* xg = (const float4*)(x + base_row * DD);
    float4* sx4 = (float4*)&sX[0][0];
    sx4[t] = xg[t];
    sx4[t + 256] = xg[t + 256];

    float acc[8];
#pragma unroll
    for (int r = 0; r < 8; ++r) acc[r] = 0.f;

    for (int ch = 0; ch < 2; ++ch) {
        __syncthreads();
        // load W chunk transposed: sW[k][o2] = W[o2][ch*64 + k]
        const float4* wg = (const float4*)W;
#pragma unroll
        for (int i = 0; i < 8; ++i) {
            int f = t + i * 256;          // 0..2047
            int o2 = f >> 4;
            int kq = f & 15;
            float4 v = wg[o2 * 32 + ch * 16 + kq];
            sW[kq * 4 + 0][o2] = v.x;
            sW[kq * 4 + 1][o2] = v.y;
            sW[kq * 4 + 2][o2] = v.z;
            sW[kq * 4 + 3][o2] = v.w;
        }
        __syncthreads();
#pragma unroll
        for (int k4 = 0; k4 < 16; ++k4) {
            float w0 = sW[k4 * 4 + 0][o];
            float w1 = sW[k4 * 4 + 1][o];
            float w2 = sW[k4 * 4 + 2][o];
            float w3 = sW[k4 * 4 + 3][o];
#pragma unroll
            for (int r = 0; r < 8; ++r) {
                const float4 xv = *(const float4*)&sX[rg * 8 + r][ch * 64 + k4 * 4];
                acc[r] = fmaf(xv.x, w0, fmaf(xv.y, w1, fmaf(xv.z, w2, fmaf(xv.w, w3, acc[r]))));
            }
        }
    }
#pragma unroll
    for (int r = 0; r < 8; ++r) {
        size_t row = base_row + rg * 8 + r;
        h[row * DD + o] = acc[r];
    }
}

// one edge per 32 lanes; float4 gather of h[row], 4 atomicAdds into agg[col]
__global__ __launch_bounds__(256) void k_agg(const float* __restrict__ h,
                                             const int* __restrict__ ei,
                                             const int* __restrict__ flag,
                                             const float* __restrict__ dinv,
                                             float* __restrict__ agg, int E) {
    int e = blockIdx.x * 8 + (threadIdx.x >> 5);
    if (e >= E) return;
    int lane = threadIdx.x & 31;
    int f = *flag;
    int r, c;
    if (f) { r = ei[2 * e]; c = ei[2 * (E + e)]; }
    else   { r = ei[e];     c = ei[E + e]; }
    float nrm = dinv[r] * dinv[c];
    float4 v = ((const float4*)(h + (size_t)r * DD))[lane];
    float* dst = agg + (size_t)c * DD + lane * 4;
    atomicAdd(dst + 0, nrm * v.x);
    atomicAdd(dst + 1, nrm * v.y);
    atomicAdd(dst + 2, nrm * v.z);
    atomicAdd(dst + 3, nrm * v.w);
}

__global__ __launch_bounds__(256) void k_stats(const float* __restrict__ agg,
                                               const float* __restrict__ bias,
                                               float* __restrict__ colsum,
                                               float* __restrict__ colsumsq) {
    int t = threadIdx.x;
    int c = t & 127;
    int half = t >> 7;
    float b = bias[c];
    float s = 0.f, sq = 0.f;
    int rowstep = gridDim.x * 2;
    for (int r = blockIdx.x * 2 + half; r < NN; r += rowstep) {
        float v = agg[(size_t)r * DD + c] + b;
        s += v;
        sq += v * v;
    }
    __shared__ float ls[256], lq[256];
    ls[t] = s; lq[t] = sq;
    __syncthreads();
    if (t < 128) {
        atomicAdd(&colsum[c], ls[t] + ls[t + 128]);
        atomicAdd(&colsumsq[c], lq[t] + lq[t + 128]);
    }
}

__global__ __launch_bounds__(256) void k_final(const float* __restrict__ agg,
                                               const float* __restrict__ x,
                                               const float* __restrict__ bias,
                                               const float* __restrict__ gamma,
                                               const float* __restrict__ beta,
                                               const float* __restrict__ colsum,
                                               const float* __restrict__ colsumsq,
                                               float* __restrict__ out, int out_size) {
    int gid = blockIdx.x * 256 + threadIdx.x;     // float4 index, ND/4 total
    int c4 = (gid & 31) * 4;
    const float4 a = ((const float4*)agg)[gid];
    const float4 xv = ((const float4*)x)[gid];
    const float invN = 1.0f / NN;
    float4 o;
#define BN1(comp, j)                                                        \
    {                                                                       \
        float m = colsum[c4 + j] * invN;                                    \
        float var = colsumsq[c4 + j] * invN - m * m;                        \
        float inv = rsqrtf(var + BN_EPS);                                   \
        float val = (a.comp + bias[c4 + j] - m) * inv * gamma[c4 + j] +     \
                    beta[c4 + j];                                           \
        val = fmaxf(val, 0.f);                                              \
        o.comp = val + xv.comp;                                             \
    }
    BN1(x, 0) BN1(y, 1) BN1(z, 2) BN1(w, 3)
#undef BN1
    ((float4*)out)[gid] = o;
    if (gid == 0 && out_size > ND) out[ND] = 0.0f;   // tuple's second output: 0
}

extern "C" void kernel_launch(void* const* d_in, const int* in_sizes, int n_in,
                              void* d_out, int out_size, void* d_ws, size_t ws_size,
                              hipStream_t stream) {
    const float* x     = (const float*)d_in[0];
    const int*   ei    = (const int*)d_in[1];
    const float* W     = (const float*)d_in[2];
    const float* bias  = (const float*)d_in[3];
    const float* gamma = (const float*)d_in[4];
    const float* beta  = (const float*)d_in[5];
    float* ws = (float*)d_ws;

    float* agg      = ws;
    float* deg      = ws + ND;
    float* colsum   = ws + ND + NN;
    float* colsumsq = colsum + 128;
    int*   flag     = (int*)(colsum + 256);
    float* dinv     = ws + ND + NN + 320;
    float* h        = dinv + NN;
    float* out = (float*)d_out;

    int E = in_sizes[1] / 2;

    hipMemsetAsync(d_ws, 0, (size_t)(ND + NN + 320) * sizeof(float), stream);
    k_detect<<<1, 64, 0, stream>>>(ei, flag);
    k_deg<<<(E + 255) / 256, 256, 0, stream>>>(ei, flag, deg, E);
    k_dinv<<<(NN + 255) / 256, 256, 0, stream>>>(deg, dinv);
    k_gemm<<<NN / 16, 256, 0, stream>>>(x, W, h);
    k_agg<<<(E + 7) / 8, 256, 0, stream>>>(h, ei, flag, dinv, agg, E);
    k_stats<<<1024, 256, 0, stream>>>(agg, bias, colsum, colsumsq);
    k_final<<<ND / (256 * 4), 256, 0, stream>>>(agg, x, bias, gamma, beta,
                                                colsum, colsumsq, out, out_size);
}

// Round 2
// 460.386 us; speedup vs baseline: 3.5947x; 3.5947x over previous
//
#include <hip/hip_runtime.h>
#include <cstddef>

#define NN 100000
#define DD 128
#define ND (NN * DD)
#define EE_SCAN_NB 98          // ceil(100000/1024)
#define BN_EPS 1e-5f

// ws 4-byte-slot layout:
//   [0, ND)                     agg (gather writes S*x, gemm transforms in-place)
//   [ND, +128)                  colsum   (zeroed)
//   [ND+128, +128)              colsumsq (zeroed)
//   [ND+256, +NN)               cnt  (int, zeroed)   <- memset covers ND .. ND+256+NN
//   [ND+256+NN, +NN)            ptr0 (int, segment starts)
//   [ND+256+2NN, +NN)           pcur (int, running cursors)
//   [ND+256+3NN, +NN)           dinv (float)
//   [ND+256+4NN, +128)          bsum (int, scan block sums)
//   ND+384+4NN                  flag (int, written unconditionally)
//   [ND+385+4NN, +E)            srow (int, dest-sorted source node ids)

__global__ void k_detect(const int* __restrict__ ei, int* __restrict__ flag) {
    // int64 storage => high word of every entry is 0 (ids < 100000).
    if (threadIdx.x == 0) {
        int allz = 1;
        for (int i = 0; i < 64; ++i)
            if (ei[2 * i + 1] != 0) { allz = 0; break; }
        *flag = allz;
    }
}

__global__ __launch_bounds__(256) void k_hist(const int* __restrict__ ei,
                                              const int* __restrict__ flag,
                                              int* __restrict__ cnt, int E) {
    int e = blockIdx.x * 256 + threadIdx.x;
    if (e >= E) return;
    int f = *flag;
    int c = f ? ei[2 * (E + e)] : ei[E + e];
    atomicAdd(&cnt[c], 1);
}

__global__ __launch_bounds__(256) void k_scan1(const int* __restrict__ cnt,
                                               int* __restrict__ bsum) {
    int t = threadIdx.x;
    int base = blockIdx.x * 1024 + t * 4;
    int s = 0;
#pragma unroll
    for (int i = 0; i < 4; ++i) {
        int idx = base + i;
        if (idx < NN) s += cnt[idx];
    }
    __shared__ int ls[256];
    ls[t] = s;
    __syncthreads();
    for (int o = 128; o > 0; o >>= 1) {
        if (t < o) ls[t] += ls[t + o];
        __syncthreads();
    }
    if (t == 0) bsum[blockIdx.x] = ls[0];
}

__global__ void k_scan2(int* __restrict__ bsum) {
    int t = threadIdx.x;
    __shared__ int ls[EE_SCAN_NB];
    if (t < EE_SCAN_NB) ls[t] = bsum[t];
    __syncthreads();
    if (t == 0) {
        int run = 0;
        for (int i = 0; i < EE_SCAN_NB; ++i) { int v = ls[i]; ls[i] = run; run += v; }
    }
    __syncthreads();
    if (t < EE_SCAN_NB) bsum[t] = ls[t];
}

__global__ __launch_bounds__(256) void k_scan3(const int* __restrict__ cnt,
                                               const int* __restrict__ bsum,
                                               int* __restrict__ ptr0,
                                               int* __restrict__ pcur) {
    int t = threadIdx.x;
    int base = blockIdx.x * 1024 + t * 4;
    int c[4];
    int lsum = 0;
#pragma unroll
    for (int i = 0; i < 4; ++i) {
        int idx = base + i;
        c[i] = (idx < NN) ? cnt[idx] : 0;
        lsum += c[i];
    }
    __shared__ int ls[256];
    ls[t] = lsum;
    __syncthreads();
    // Hillis-Steele inclusive scan over 256 thread sums
    for (int o = 1; o < 256; o <<= 1) {
        int v = (t >= o) ? ls[t - o] : 0;
        __syncthreads();
        ls[t] += v;
        __syncthreads();
    }
    int run = ls[t] - lsum + bsum[blockIdx.x];   // exclusive offset
#pragma unroll
    for (int i = 0; i < 4; ++i) {
        int idx = base + i;
        if (idx < NN) { ptr0[idx] = run; pcur[idx] = run; }
        run += c[i];
    }
}

__global__ void k_dinv(const int* __restrict__ cnt, float* __restrict__ dinv) {
    int i = blockIdx.x * 256 + threadIdx.x;
    if (i < NN) {
        int d = cnt[i];
        dinv[i] = d > 0 ? rsqrtf((float)d) : 0.f;
    }
}

__global__ __launch_bounds__(256) void k_scatter(const int* __restrict__ ei,
                                                 const int* __restrict__ flag,
                                                 int* __restrict__ pcur,
                                                 int* __restrict__ srow, int E) {
    int e = blockIdx.x * 256 + threadIdx.x;
    if (e >= E) return;
    int f = *flag;
    int r, c;
    if (f) { r = ei[2 * e]; c = ei[2 * (E + e)]; }
    else   { r = ei[e];     c = ei[E + e]; }
    int p = atomicAdd(&pcur[c], 1);
    srow[p] = r;
}

// one wave (64 lanes) per node; lane l holds cols {2l, 2l+1}; no atomics
__global__ __launch_bounds__(256) void k_gather(const float* __restrict__ x,
                                                const int* __restrict__ srow,
                                                const int* __restrict__ ptr0,
                                                const int* __restrict__ cnt,
                                                const float* __restrict__ dinv,
                                                float* __restrict__ agg) {
    int n = blockIdx.x * 4 + (threadIdx.x >> 6);
    int lane = threadIdx.x & 63;
    int s = ptr0[n];
    int k = cnt[n];
    const float2* x2 = (const float2*)x;
    float ax = 0.f, ay = 0.f;
    for (int j = 0; j < k; ++j) {
        int r = srow[s + j];
        float w = dinv[r];
        float2 v = x2[(size_t)r * 64 + lane];
        ax = fmaf(w, v.x, ax);
        ay = fmaf(w, v.y, ay);
    }
    float dc = dinv[n];
    float2 o; o.x = dc * ax; o.y = dc * ay;
    ((float2*)agg)[(size_t)n * 64 + lane] = o;
}

// in-place: agg <- agg @ W^T   (W: [out][in] row-major)
// Safe in-place: each block stages its 16 rows into LDS before any global write.
__global__ __launch_bounds__(256) void k_gemm(float* hh, const float* __restrict__ W) {
    __shared__ float sX[16][128];
    __shared__ float sW[64][129];
    int t = threadIdx.x;
    int o = t & 127;
    int rg = t >> 7;
    size_t base_row = (size_t)blockIdx.x * 16;

    const float4* xg = (const float4*)(hh + base_row * DD);
    float4* sx4 = (float4*)&sX[0][0];
    sx4[t] = xg[t];
    sx4[t + 256] = xg[t + 256];

    float acc[8];
#pragma unroll
    for (int r = 0; r < 8; ++r) acc[r] = 0.f;

    for (int ch = 0; ch < 2; ++ch) {
        __syncthreads();
        const float4* wg = (const float4*)W;
#pragma unroll
        for (int i = 0; i < 8; ++i) {
            int f = t + i * 256;
            int o2 = f >> 4;
            int kq = f & 15;
            float4 v = wg[o2 * 32 + ch * 16 + kq];
            sW[kq * 4 + 0][o2] = v.x;
            sW[kq * 4 + 1][o2] = v.y;
            sW[kq * 4 + 2][o2] = v.z;
            sW[kq * 4 + 3][o2] = v.w;
        }
        __syncthreads();
#pragma unroll
        for (int k4 = 0; k4 < 16; ++k4) {
            float w0 = sW[k4 * 4 + 0][o];
            float w1 = sW[k4 * 4 + 1][o];
            float w2 = sW[k4 * 4 + 2][o];
            float w3 = sW[k4 * 4 + 3][o];
#pragma unroll
            for (int r = 0; r < 8; ++r) {
                const float4 xv = *(const float4*)&sX[rg * 8 + r][ch * 64 + k4 * 4];
                acc[r] = fmaf(xv.x, w0, fmaf(xv.y, w1, fmaf(xv.z, w2, fmaf(xv.w, w3, acc[r]))));
            }
        }
    }
#pragma unroll
    for (int r = 0; r < 8; ++r) {
        size_t row = base_row + rg * 8 + r;
        hh[row * DD + o] = acc[r];
    }
}

__global__ __launch_bounds__(256) void k_stats(const float* __restrict__ agg,
                                               const float* __restrict__ bias,
                                               float* __restrict__ colsum,
                                               float* __restrict__ colsumsq) {
    int t = threadIdx.x;
    int c = t & 127;
    int half = t >> 7;
    float b = bias[c];
    float s = 0.f, sq = 0.f;
    int rowstep = gridDim.x * 2;
    for (int r = blockIdx.x * 2 + half; r < NN; r += rowstep) {
        float v = agg[(size_t)r * DD + c] + b;
        s += v;
        sq += v * v;
    }
    __shared__ float ls[256], lq[256];
    ls[t] = s; lq[t] = sq;
    __syncthreads();
    if (t < 128) {
        atomicAdd(&colsum[c], ls[t] + ls[t + 128]);
        atomicAdd(&colsumsq[c], lq[t] + lq[t + 128]);
    }
}

__global__ __launch_bounds__(256) void k_final(const float* __restrict__ agg,
                                               const float* __restrict__ x,
                                               const float* __restrict__ bias,
                                               const float* __restrict__ gamma,
                                               const float* __restrict__ beta,
                                               const float* __restrict__ colsum,
                                               const float* __restrict__ colsumsq,
                                               float* __restrict__ out, int out_size) {
    int gid = blockIdx.x * 256 + threadIdx.x;     // float4 index
    int c4 = (gid & 31) * 4;
    const float4 a = ((const float4*)agg)[gid];
    const float4 xv = ((const float4*)x)[gid];
    const float invN = 1.0f / NN;
    float4 o;
#define BN1(comp, j)                                                        \
    {                                                                       \
        float m = colsum[c4 + j] * invN;                                    \
        float var = colsumsq[c4 + j] * invN - m * m;                        \
        float inv = rsqrtf(var + BN_EPS);                                   \
        float val = (a.comp + bias[c4 + j] - m) * inv * gamma[c4 + j] +     \
                    beta[c4 + j];                                           \
        val = fmaxf(val, 0.f);                                              \
        o.comp = val + xv.comp;                                             \
    }
    BN1(x, 0) BN1(y, 1) BN1(z, 2) BN1(w, 3)
#undef BN1
    ((float4*)out)[gid] = o;
    if (gid == 0 && out_size > ND) out[ND] = 0.0f;
}

extern "C" void kernel_launch(void* const* d_in, const int* in_sizes, int n_in,
                              void* d_out, int out_size, void* d_ws, size_t ws_size,
                              hipStream_t stream) {
    const float* x     = (const float*)d_in[0];
    const int*   ei    = (const int*)d_in[1];
    const float* W     = (const float*)d_in[2];
    const float* bias  = (const float*)d_in[3];
    const float* gamma = (const float*)d_in[4];
    const float* beta  = (const float*)d_in[5];
    float* ws = (float*)d_ws;
    float* out = (float*)d_out;

    float* agg      = ws;
    float* colsum   = ws + ND;
    float* colsumsq = colsum + 128;
    int*   cnt      = (int*)(ws + ND + 256);
    int*   ptr0     = cnt + NN;
    int*   pcur     = ptr0 + NN;
    float* dinv     = (float*)(pcur + NN);
    int*   bsum     = (int*)(dinv + NN);
    int*   flag     = bsum + 128;
    int*   srow     = flag + 1;

    int E = in_sizes[1] / 2;

    // zero: colsum/colsumsq (256 floats) + cnt (NN ints)
    hipMemsetAsync(colsum, 0, (size_t)(256 + NN) * 4, stream);
    k_detect<<<1, 64, 0, stream>>>(ei, flag);
    k_hist<<<(E + 255) / 256, 256, 0, stream>>>(ei, flag, cnt, E);
    k_scan1<<<EE_SCAN_NB, 256, 0, stream>>>(cnt, bsum);
    k_scan2<<<1, 128, 0, stream>>>(bsum);
    k_scan3<<<EE_SCAN_NB, 256, 0, stream>>>(cnt, bsum, ptr0, pcur);
    k_dinv<<<(NN + 255) / 256, 256, 0, stream>>>(cnt, dinv);
    k_scatter<<<(E + 255) / 256, 256, 0, stream>>>(ei, flag, pcur, srow, E);
    k_gather<<<NN / 4, 256, 0, stream>>>(x, srow, ptr0, cnt, dinv, agg);
    k_gemm<<<NN / 16, 256, 0, stream>>>(agg, W);
    k_stats<<<1024, 256, 0, stream>>>(agg, bias, colsum, colsumsq);
    k_final<<<ND / (256 * 4), 256, 0, stream>>>(agg, x, bias, gamma, beta,
                                                colsum, colsumsq, out, out_size);
}

// Round 3
// 381.257 us; speedup vs baseline: 4.3408x; 1.2075x over previous
//
#include <hip/hip_runtime.h>
#include <cstddef>

#define NN 100000
#define DD 128
#define ND (NN * DD)
#define EE_SCAN_NB 98          // ceil(100000/1024)
#define BN_EPS 1e-5f
#define LDA 136                // LDS A row stride in bf16 elems (272 B, 16B-aligned)

typedef __bf16 bf16_t;
typedef bf16_t bf16x8 __attribute__((ext_vector_type(8)));
typedef float f32x4 __attribute__((ext_vector_type(4)));
typedef unsigned int uint;
typedef unsigned short ushort;

// ws 4-byte-slot layout:
//   [0, ND/2)                 hb   (bf16 h = agg@W^T, packed [NN][128])
//   [ND/2, ND)                xb   (bf16 x)
//   [ND, 3ND/2)               aggb (bf16 S*x)
//   base3 = 3ND/2:
//   [base3, +128)             colsum   (zeroed)
//   [base3+128, +128)         colsumsq (zeroed)
//   [base3+256, +NN)          cnt  (int, zeroed)    <- one memset covers base3..+256+NN
//   [base3+256+NN, +NN)       ptr0
//   [base3+256+2NN, +NN)      pcur
//   [base3+256+3NN, +NN)      dinv (float)
//   [base3+256+4NN, +128)     bsum
//   base3+256+4NN+128         flag
//   [base3+256+4NN+132, +E)   srow (dest-sorted source ids)
//   [.. end, +8192)           wb   (bf16 W, 16384 elems)

__device__ __forceinline__ ushort f2b(float f) {
    uint u = __builtin_bit_cast(uint, f);
    u += 0x7FFFu + ((u >> 16) & 1u);          // RNE
    return (ushort)(u >> 16);
}
__device__ __forceinline__ float b2f(uint s) {
    return __builtin_bit_cast(float, s << 16);
}

__global__ void k_detect(const int* __restrict__ ei, int* __restrict__ flag) {
    // int64 storage => high word of every entry is 0 (ids < 100000).
    if (threadIdx.x == 0) {
        int allz = 1;
        for (int i = 0; i < 64; ++i)
            if (ei[2 * i + 1] != 0) { allz = 0; break; }
        *flag = allz;
    }
}

__global__ __launch_bounds__(256) void k_hist(const int* __restrict__ ei,
                                              const int* __restrict__ flag,
                                              int* __restrict__ cnt, int E) {
    int e = blockIdx.x * 256 + threadIdx.x;
    if (e >= E) return;
    int f = *flag;
    int c = f ? ei[2 * (E + e)] : ei[E + e];
    atomicAdd(&cnt[c], 1);
}

__global__ __launch_bounds__(256) void k_scan1(const int* __restrict__ cnt,
                                               int* __restrict__ bsum) {
    int t = threadIdx.x;
    int base = blockIdx.x * 1024 + t * 4;
    int s = 0;
#pragma unroll
    for (int i = 0; i < 4; ++i) {
        int idx = base + i;
        if (idx < NN) s += cnt[idx];
    }
    __shared__ int ls[256];
    ls[t] = s;
    __syncthreads();
    for (int o = 128; o > 0; o >>= 1) {
        if (t < o) ls[t] += ls[t + o];
        __syncthreads();
    }
    if (t == 0) bsum[blockIdx.x] = ls[0];
}

__global__ void k_scan2(int* __restrict__ bsum) {
    int t = threadIdx.x;
    __shared__ int ls[EE_SCAN_NB];
    if (t < EE_SCAN_NB) ls[t] = bsum[t];
    __syncthreads();
    if (t == 0) {
        int run = 0;
        for (int i = 0; i < EE_SCAN_NB; ++i) { int v = ls[i]; ls[i] = run; run += v; }
    }
    __syncthreads();
    if (t < EE_SCAN_NB) bsum[t] = ls[t];
}

__global__ __launch_bounds__(256) void k_scan3(const int* __restrict__ cnt,
                                               const int* __restrict__ bsum,
                                               int* __restrict__ ptr0,
                                               int* __restrict__ pcur) {
    int t = threadIdx.x;
    int base = blockIdx.x * 1024 + t * 4;
    int c[4];
    int lsum = 0;
#pragma unroll
    for (int i = 0; i < 4; ++i) {
        int idx = base + i;
        c[i] = (idx < NN) ? cnt[idx] : 0;
        lsum += c[i];
    }
    __shared__ int ls[256];
    ls[t] = lsum;
    __syncthreads();
    for (int o = 1; o < 256; o <<= 1) {
        int v = (t >= o) ? ls[t - o] : 0;
        __syncthreads();
        ls[t] += v;
        __syncthreads();
    }
    int run = ls[t] - lsum + bsum[blockIdx.x];
#pragma unroll
    for (int i = 0; i < 4; ++i) {
        int idx = base + i;
        if (idx < NN) { ptr0[idx] = run; pcur[idx] = run; }
        run += c[i];
    }
}

__global__ void k_dinv(const int* __restrict__ cnt, float* __restrict__ dinv) {
    int i = blockIdx.x * 256 + threadIdx.x;
    if (i < NN) {
        int d = cnt[i];
        dinv[i] = d > 0 ? rsqrtf((float)d) : 0.f;
    }
}

__global__ __launch_bounds__(256) void k_scatter(const int* __restrict__ ei,
                                                 const int* __restrict__ flag,
                                                 int* __restrict__ pcur,
                                                 int* __restrict__ srow, int E) {
    int e = blockIdx.x * 256 + threadIdx.x;
    if (e >= E) return;
    int f = *flag;
    int r, c;
    if (f) { r = ei[2 * e]; c = ei[2 * (E + e)]; }
    else   { r = ei[e];     c = ei[E + e]; }
    int p = atomicAdd(&pcur[c], 1);
    srow[p] = r;
}

// fp32 -> bf16 pack, 8 elems/thread
__global__ __launch_bounds__(256) void k_cvt(const float* __restrict__ src,
                                             uint* __restrict__ dst, int n8) {
    int i = blockIdx.x * 256 + threadIdx.x;
    if (i >= n8) return;
    const float4* s4 = (const float4*)src;
    float4 a = s4[2 * i], b = s4[2 * i + 1];
    uint4 o;
    o.x = (uint)f2b(a.x) | ((uint)f2b(a.y) << 16);
    o.y = (uint)f2b(a.z) | ((uint)f2b(a.w) << 16);
    o.z = (uint)f2b(b.x) | ((uint)f2b(b.y) << 16);
    o.w = (uint)f2b(b.z) | ((uint)f2b(b.w) << 16);
    ((uint4*)dst)[i] = o;
}

// one wave per node; lane holds cols {2l, 2l+1} as one packed uint; no atomics
__global__ __launch_bounds__(256) void k_gather(const uint* __restrict__ xb,
                                                const int* __restrict__ srow,
                                                const int* __restrict__ ptr0,
                                                const int* __restrict__ cnt,
                                                const float* __restrict__ dinv,
                                                uint* __restrict__ aggb) {
    int n = blockIdx.x * 4 + (threadIdx.x >> 6);
    int lane = threadIdx.x & 63;
    int s = ptr0[n];
    int k = cnt[n];
    float ax = 0.f, ay = 0.f;
    for (int j = 0; j < k; ++j) {
        int r = srow[s + j];
        float w = dinv[r];
        uint v = xb[(size_t)r * 64 + lane];
        ax = fmaf(w, b2f(v & 0xFFFFu), ax);
        ay = fmaf(w, b2f(v >> 16), ay);
    }
    float dc = dinv[n];
    aggb[(size_t)n * 64 + lane] = (uint)f2b(dc * ax) | ((uint)f2b(dc * ay) << 16);
}

// hb = aggb @ W^T via MFMA bf16. Block = 256 thr = 4 waves, 64 rows/block.
// W (bf16) fragments hoisted to 128 VGPRs (block-invariant, L1-resident).
__global__ __launch_bounds__(256, 2) void k_gemm(const ushort* __restrict__ aggb,
                                                 const ushort* __restrict__ wb,
                                                 ushort* __restrict__ hb) {
    __shared__ ushort sA[64 * LDA];           // 17.4 KB
    int t = threadIdx.x;
    int wave = t >> 6, lane = t & 63;
    int quad = lane >> 4, l16 = lane & 15;
    size_t rowbase = (size_t)blockIdx.x * 64;

    // B frags: Bf[ct][ks] holds W[ct*16+l16][ks*32 + quad*8 + 0..7]
    bf16x8 Bf[8][4];
#pragma unroll
    for (int ct = 0; ct < 8; ++ct)
#pragma unroll
        for (int ks = 0; ks < 4; ++ks) {
            const uint4* p =
                (const uint4*)(wb + (size_t)(ct * 16 + l16) * 128 + ks * 32 + quad * 8);
            Bf[ct][ks] = __builtin_bit_cast(bf16x8, *p);
        }

    // stage A: 64 rows x 128 bf16 -> LDS (stride LDA)
#pragma unroll
    for (int i = 0; i < 4; ++i) {
        int c = t + i * 256;                  // 16B-chunk id, 1024 total
        int r = c >> 4, pos = c & 15;
        size_t gr = rowbase + r;
        if (gr >= NN) gr = NN - 1;
        uint4 v = *(const uint4*)(aggb + gr * 128 + pos * 8);
        *(uint4*)(sA + r * LDA + pos * 8) = v;
    }
    __syncthreads();

    // A frags: row = wave*16 + l16, k = ks*32 + quad*8
    bf16x8 Af[4];
#pragma unroll
    for (int ks = 0; ks < 4; ++ks)
        Af[ks] = __builtin_bit_cast(
            bf16x8, *(const uint4*)(sA + (wave * 16 + l16) * LDA + ks * 32 + quad * 8));

    f32x4 acc[8];
#pragma unroll
    for (int ct = 0; ct < 8; ++ct) {
        acc[ct] = (f32x4){0.f, 0.f, 0.f, 0.f};
#pragma unroll
        for (int ks = 0; ks < 4; ++ks)
            acc[ct] = __builtin_amdgcn_mfma_f32_16x16x32_bf16(Af[ks], Bf[ct][ks],
                                                              acc[ct], 0, 0, 0);
    }

    // C layout: col = ct*16 + l16, row = rowbase + wave*16 + quad*4 + r
#pragma unroll
    for (int ct = 0; ct < 8; ++ct)
#pragma unroll
        for (int r = 0; r < 4; ++r) {
            size_t row = rowbase + wave * 16 + quad * 4 + r;
            if (row < NN) hb[row * 128 + ct * 16 + l16] = f2b(acc[ct][r]);
        }
}

// column sums / sumsq of bf16 h (bias cancels inside BN, omitted)
__global__ __launch_bounds__(256) void k_stats(const uint* __restrict__ hb2,
                                               float* __restrict__ colsum,
                                               float* __restrict__ colsumsq) {
    int t = threadIdx.x;
    int u = t & 63;                 // packed-uint col index (cols 2u, 2u+1)
    int rg = t >> 6;
    float s0 = 0.f, s1 = 0.f, q0 = 0.f, q1 = 0.f;
    int rowstep = gridDim.x * 4;
    for (int r = blockIdx.x * 4 + rg; r < NN; r += rowstep) {
        uint v = hb2[(size_t)r * 64 + u];
        float a = b2f(v & 0xFFFFu), b = b2f(v >> 16);
        s0 += a; q0 += a * a;
        s1 += b; q1 += b * b;
    }
    __shared__ float ls[4][128], lq[4][128];
    ls[rg][2 * u] = s0; ls[rg][2 * u + 1] = s1;
    lq[rg][2 * u] = q0; lq[rg][2 * u + 1] = q1;
    __syncthreads();
    if (t < 128) {
        float s = ls[0][t] + ls[1][t] + ls[2][t] + ls[3][t];
        float q = lq[0][t] + lq[1][t] + lq[2][t] + lq[3][t];
        atomicAdd(&colsum[t], s);
        atomicAdd(&colsumsq[t], q);
    }
}

__global__ __launch_bounds__(256) void k_final(const uint* __restrict__ hb,
                                               const float* __restrict__ x,
                                               const float* __restrict__ gamma,
                                               const float* __restrict__ beta,
                                               const float* __restrict__ colsum,
                                               const float* __restrict__ colsumsq,
                                               float* __restrict__ out, int out_size) {
    int gid = blockIdx.x * 256 + threadIdx.x;     // float4 index over ND/4
    int c4 = (gid & 31) * 4;
    uint2 hv = ((const uint2*)hb)[gid];
    const float4 xv = ((const float4*)x)[gid];
    float hval[4] = { b2f(hv.x & 0xFFFFu), b2f(hv.x >> 16),
                      b2f(hv.y & 0xFFFFu), b2f(hv.y >> 16) };
    const float invN = 1.0f / NN;
    float4 o;
    float res[4];
#pragma unroll
    for (int j = 0; j < 4; ++j) {
        float m = colsum[c4 + j] * invN;
        float var = colsumsq[c4 + j] * invN - m * m;
        float inv = rsqrtf(var + BN_EPS);
        float val = (hval[j] - m) * inv * gamma[c4 + j] + beta[c4 + j];
        res[j] = fmaxf(val, 0.f);
    }
    o.x = res[0] + xv.x; o.y = res[1] + xv.y;
    o.z = res[2] + xv.z; o.w = res[3] + xv.w;
    ((float4*)out)[gid] = o;
    if (gid == 0 && out_size > ND) out[ND] = 0.0f;
}

extern "C" void kernel_launch(void* const* d_in, const int* in_sizes, int n_in,
                              void* d_out, int out_size, void* d_ws, size_t ws_size,
                              hipStream_t stream) {
    const float* x     = (const float*)d_in[0];
    const int*   ei    = (const int*)d_in[1];
    const float* W     = (const float*)d_in[2];
    const float* gamma = (const float*)d_in[4];
    const float* beta  = (const float*)d_in[5];
    float* ws = (float*)d_ws;
    float* out = (float*)d_out;

    uint*   hb       = (uint*)ws;                      // ND/2 slots
    uint*   xb       = (uint*)(ws + ND / 2);           // ND/2 slots
    uint*   aggb     = (uint*)(ws + ND);               // ND/2 slots
    float*  colsum   = ws + 3 * (size_t)ND / 2;
    float*  colsumsq = colsum + 128;
    int*    cnt      = (int*)(colsumsq + 128);
    int*    ptr0     = cnt + NN;
    int*    pcur     = ptr0 + NN;
    float*  dinv     = (float*)(pcur + NN);
    int*    bsum     = (int*)(dinv + NN);
    int*    flag     = bsum + 128;
    int*    srow     = flag + 4;                       // keep 16B alignment downstream

    int E = in_sizes[1] / 2;
    ushort* wb = (ushort*)(srow + E);                  // 16384 bf16

    // zero colsum/colsumsq (256 floats) + cnt (NN ints)
    hipMemsetAsync(colsum, 0, (size_t)(256 + NN) * 4, stream);
    k_detect<<<1, 64, 0, stream>>>(ei, flag);
    k_hist<<<(E + 255) / 256, 256, 0, stream>>>(ei, flag, cnt, E);
    k_scan1<<<EE_SCAN_NB, 256, 0, stream>>>(cnt, bsum);
    k_scan2<<<1, 128, 0, stream>>>(bsum);
    k_scan3<<<EE_SCAN_NB, 256, 0, stream>>>(cnt, bsum, ptr0, pcur);
    k_dinv<<<(NN + 255) / 256, 256, 0, stream>>>(cnt, dinv);
    k_scatter<<<(E + 255) / 256, 256, 0, stream>>>(ei, flag, pcur, srow, E);
    k_cvt<<<ND / 8 / 256, 256, 0, stream>>>(x, xb, ND / 8);
    k_cvt<<<8, 256, 0, stream>>>(W, (uint*)wb, (DD * DD) / 8);
    k_gather<<<NN / 4, 256, 0, stream>>>(xb, srow, ptr0, cnt, dinv, aggb);
    k_gemm<<<(NN + 63) / 64, 256, 0, stream>>>((const ushort*)aggb, wb, (ushort*)hb);
    k_stats<<<1024, 256, 0, stream>>>(hb, colsum, colsumsq);
    k_final<<<ND / (256 * 4), 256, 0, stream>>>(hb, x, gamma, beta,
                                                colsum, colsumsq, out, out_size);
}

// Round 4
// 307.468 us; speedup vs baseline: 5.3825x; 1.2400x over previous
//
#include <hip/hip_runtime.h>
#include <cstddef>

#define NN 100000
#define DD 128
#define ND (NN * DD)
#define EE_SCAN_NB 98          // ceil(100000/1024)
#define BN_EPS 1e-5f
#define LDA 136                // LDS A row stride in bf16 elems (272 B, 16B-aligned)

typedef __bf16 bf16_t;
typedef bf16_t bf16x8 __attribute__((ext_vector_type(8)));
typedef float f32x4 __attribute__((ext_vector_type(4)));
typedef unsigned int uint;
typedef unsigned short ushort;

// ws 4-byte-slot layout:
//   [0, ND/2)                 hb   (bf16 h, packed [NN][128])
//   [ND/2, ND)                xb   (bf16 x)
//   [ND, 3ND/2)               aggb (bf16 S*x)
//   base3 = 3ND/2:
//   [base3, +128)             colsum   (zeroed)
//   [base3+128, +128)         colsumsq (zeroed)
//   [base3+256, +NN)          cnt  (int, zeroed)   <- one memset covers base3..+256+NN
//   [base3+256+NN, +NN)       ptr0
//   [base3+256+2NN, +NN)      pcur
//   [base3+256+3NN, +NN)      dinv (float)
//   [base3+256+4NN, +128)     bsum
//   [base3+256+4NN+136, +2E)  edata (uint2: src id, bits(dinv[src]))  [8B aligned]
//   [.. +8192)                wb   (bf16 W)

__device__ __forceinline__ ushort f2b(float f) {
    uint u = __builtin_bit_cast(uint, f);
    u += 0x7FFFu + ((u >> 16) & 1u);          // RNE
    return (ushort)(u >> 16);
}
__device__ __forceinline__ float b2f(uint s) {
    return __builtin_bit_cast(float, s << 16);
}

// int64 edge_index => high word of every entry is 0 (ids < 100000).
// Each block re-derives the flag (L1/L2-hit after the first block).
__device__ __forceinline__ int detect_i64(const int* __restrict__ ei) {
    __shared__ int sflag;
    int t = threadIdx.x;
    if (t < 64) {
        int hi = ei[2 * t + 1];
        unsigned long long b = __ballot(hi == 0);
        if (t == 0) sflag = (b == ~0ull) ? 1 : 0;
    }
    __syncthreads();
    return sflag;
}

__global__ __launch_bounds__(256) void k_hist(const int* __restrict__ ei,
                                              int* __restrict__ cnt, int E) {
    int f = detect_i64(ei);
    int e = blockIdx.x * 256 + threadIdx.x;
    if (e >= E) return;
    int c = f ? ei[2 * (E + e)] : ei[E + e];
    atomicAdd(&cnt[c], 1);
}

__global__ __launch_bounds__(256) void k_scan1(const int* __restrict__ cnt,
                                               int* __restrict__ bsum) {
    int t = threadIdx.x;
    int base = blockIdx.x * 1024 + t * 4;
    int s = 0;
#pragma unroll
    for (int i = 0; i < 4; ++i) {
        int idx = base + i;
        if (idx < NN) s += cnt[idx];
    }
    __shared__ int ls[256];
    ls[t] = s;
    __syncthreads();
    for (int o = 128; o > 0; o >>= 1) {
        if (t < o) ls[t] += ls[t + o];
        __syncthreads();
    }
    if (t == 0) bsum[blockIdx.x] = ls[0];
}

__global__ void k_scan2(int* __restrict__ bsum) {
    int t = threadIdx.x;
    __shared__ int ls[EE_SCAN_NB];
    if (t < EE_SCAN_NB) ls[t] = bsum[t];
    __syncthreads();
    if (t == 0) {
        int run = 0;
        for (int i = 0; i < EE_SCAN_NB; ++i) { int v = ls[i]; ls[i] = run; run += v; }
    }
    __syncthreads();
    if (t < EE_SCAN_NB) bsum[t] = ls[t];
}

__global__ __launch_bounds__(256) void k_scan3(const int* __restrict__ cnt,
                                               const int* __restrict__ bsum,
                                               int* __restrict__ ptr0,
                                               int* __restrict__ pcur,
                                               float* __restrict__ dinv) {
    int t = threadIdx.x;
    int base = blockIdx.x * 1024 + t * 4;
    int c[4];
    int lsum = 0;
#pragma unroll
    for (int i = 0; i < 4; ++i) {
        int idx = base + i;
        c[i] = (idx < NN) ? cnt[idx] : 0;
        lsum += c[i];
    }
    __shared__ int ls[256];
    ls[t] = lsum;
    __syncthreads();
    for (int o = 1; o < 256; o <<= 1) {
        int v = (t >= o) ? ls[t - o] : 0;
        __syncthreads();
        ls[t] += v;
        __syncthreads();
    }
    int run = ls[t] - lsum + bsum[blockIdx.x];
#pragma unroll
    for (int i = 0; i < 4; ++i) {
        int idx = base + i;
        if (idx < NN) {
            ptr0[idx] = run;
            pcur[idx] = run;
            dinv[idx] = c[i] > 0 ? rsqrtf((float)c[i]) : 0.f;
        }
        run += c[i];
    }
}

__global__ __launch_bounds__(256) void k_scatter(const int* __restrict__ ei,
                                                 const float* __restrict__ dinv,
                                                 int* __restrict__ pcur,
                                                 uint2* __restrict__ edata, int E) {
    int f = detect_i64(ei);
    int e = blockIdx.x * 256 + threadIdx.x;
    if (e >= E) return;
    int r, c;
    if (f) { r = ei[2 * e]; c = ei[2 * (E + e)]; }
    else   { r = ei[e];     c = ei[E + e]; }
    int p = atomicAdd(&pcur[c], 1);
    uint2 v;
    v.x = (uint)r;
    v.y = __builtin_bit_cast(uint, dinv[r]);
    edata[p] = v;
}

// fp32 -> bf16 pack for x (first ND/8 chunks) and W (next 2048 chunks)
__global__ __launch_bounds__(256) void k_cvt(const float* __restrict__ x,
                                             uint* __restrict__ xb,
                                             const float* __restrict__ W,
                                             uint* __restrict__ wb) {
    int i = blockIdx.x * 256 + threadIdx.x;
    const float* src;
    uint* dst;
    int j;
    if (i < ND / 8) { src = x; dst = xb; j = i; }
    else { j = i - ND / 8; if (j >= (DD * DD) / 8) return; src = W; dst = wb; }
    const float4* s4 = (const float4*)src;
    float4 a = s4[2 * j], b = s4[2 * j + 1];
    uint4 o;
    o.x = (uint)f2b(a.x) | ((uint)f2b(a.y) << 16);
    o.y = (uint)f2b(a.z) | ((uint)f2b(a.w) << 16);
    o.z = (uint)f2b(b.x) | ((uint)f2b(b.y) << 16);
    o.w = (uint)f2b(b.z) | ((uint)f2b(b.w) << 16);
    ((uint4*)dst)[j] = o;
}

// one wave per node. Lane l loads edge record s+l (one vector load covers the
// whole segment), then (r,w) broadcast via shfl; row loads issued 4-deep.
__global__ __launch_bounds__(256) void k_gather(const uint* __restrict__ xb,
                                                const uint2* __restrict__ edata,
                                                const int* __restrict__ ptr0,
                                                const int* __restrict__ cnt,
                                                const float* __restrict__ dinv,
                                                uint* __restrict__ aggb) {
    int n = blockIdx.x * 4 + (threadIdx.x >> 6);
    int lane = threadIdx.x & 63;
    int s = ptr0[n];
    int k = cnt[n];
    float dc = dinv[n];
    float ax = 0.f, ay = 0.f;
    for (int base = 0; base < k; base += 64) {
        int m = min(k - base, 64);
        uint2 ed; ed.x = 0u; ed.y = 0u;
        if (lane < m) ed = edata[s + base + lane];
        int rj = (int)ed.x;
        int wj = (int)ed.y;
        int j = 0;
        for (; j + 4 <= m; j += 4) {
            int r0 = __shfl(rj, j);     float w0 = __builtin_bit_cast(float, (uint)__shfl(wj, j));
            int r1 = __shfl(rj, j + 1); float w1 = __builtin_bit_cast(float, (uint)__shfl(wj, j + 1));
            int r2 = __shfl(rj, j + 2); float w2 = __builtin_bit_cast(float, (uint)__shfl(wj, j + 2));
            int r3 = __shfl(rj, j + 3); float w3 = __builtin_bit_cast(float, (uint)__shfl(wj, j + 3));
            uint v0 = xb[(size_t)r0 * 64 + lane];
            uint v1 = xb[(size_t)r1 * 64 + lane];
            uint v2 = xb[(size_t)r2 * 64 + lane];
            uint v3 = xb[(size_t)r3 * 64 + lane];
            ax = fmaf(w0, b2f(v0 & 0xFFFFu), ax); ay = fmaf(w0, b2f(v0 >> 16), ay);
            ax = fmaf(w1, b2f(v1 & 0xFFFFu), ax); ay = fmaf(w1, b2f(v1 >> 16), ay);
            ax = fmaf(w2, b2f(v2 & 0xFFFFu), ax); ay = fmaf(w2, b2f(v2 >> 16), ay);
            ax = fmaf(w3, b2f(v3 & 0xFFFFu), ax); ay = fmaf(w3, b2f(v3 >> 16), ay);
        }
        for (; j < m; ++j) {
            int r = __shfl(rj, j);
            float w = __builtin_bit_cast(float, (uint)__shfl(wj, j));
            uint v = xb[(size_t)r * 64 + lane];
            ax = fmaf(w, b2f(v & 0xFFFFu), ax);
            ay = fmaf(w, b2f(v >> 16), ay);
        }
    }
    aggb[(size_t)n * 64 + lane] = (uint)f2b(dc * ax) | ((uint)f2b(dc * ay) << 16);
}

// hb = aggb @ W^T via MFMA bf16 + fused column stats from fp32 accumulators.
// Block = 4 waves, 64 rows. W fragments hoisted to VGPRs (L1-resident).
__global__ __launch_bounds__(256, 2) void k_gemm(const ushort* __restrict__ aggb,
                                                 const ushort* __restrict__ wb,
                                                 ushort* __restrict__ hb,
                                                 float* __restrict__ colsum,
                                                 float* __restrict__ colsumsq) {
    __shared__ ushort sA[64 * LDA];           // 17.4 KB
    __shared__ float cp[4][128], cq[4][128];  // 4 KB
    int t = threadIdx.x;
    int wave = t >> 6, lane = t & 63;
    int quad = lane >> 4, l16 = lane & 15;
    size_t rowbase = (size_t)blockIdx.x * 64;

    bf16x8 Bf[8][4];
#pragma unroll
    for (int ct = 0; ct < 8; ++ct)
#pragma unroll
        for (int ks = 0; ks < 4; ++ks) {
            const uint4* p =
                (const uint4*)(wb + (size_t)(ct * 16 + l16) * 128 + ks * 32 + quad * 8);
            Bf[ct][ks] = __builtin_bit_cast(bf16x8, *p);
        }

    // stage A (OOB rows -> zeros so fused stats stay exact)
#pragma unroll
    for (int i = 0; i < 4; ++i) {
        int c = t + i * 256;
        int r = c >> 4, pos = c & 15;
        size_t gr = rowbase + r;
        uint4 v = {0u, 0u, 0u, 0u};
        if (gr < NN) v = *(const uint4*)(aggb + gr * 128 + pos * 8);
        *(uint4*)(sA + r * LDA + pos * 8) = v;
    }
    __syncthreads();

    bf16x8 Af[4];
#pragma unroll
    for (int ks = 0; ks < 4; ++ks)
        Af[ks] = __builtin_bit_cast(
            bf16x8, *(const uint4*)(sA + (wave * 16 + l16) * LDA + ks * 32 + quad * 8));

    f32x4 acc[8];
#pragma unroll
    for (int ct = 0; ct < 8; ++ct) {
        acc[ct] = (f32x4){0.f, 0.f, 0.f, 0.f};
#pragma unroll
        for (int ks = 0; ks < 4; ++ks)
            acc[ct] = __builtin_amdgcn_mfma_f32_16x16x32_bf16(Af[ks], Bf[ct][ks],
                                                              acc[ct], 0, 0, 0);
    }

    // store h + fused per-column stats
#pragma unroll
    for (int ct = 0; ct < 8; ++ct) {
        float ss = 0.f, qq = 0.f;
#pragma unroll
        for (int r = 0; r < 4; ++r) {
            float v = acc[ct][r];
            ss += v; qq += v * v;
            size_t row = rowbase + wave * 16 + quad * 4 + r;
            if (row < NN) hb[row * 128 + ct * 16 + l16] = f2b(v);
        }
        ss += __shfl_xor(ss, 16); ss += __shfl_xor(ss, 32);
        qq += __shfl_xor(qq, 16); qq += __shfl_xor(qq, 32);
        if (quad == 0) { cp[wave][ct * 16 + l16] = ss; cq[wave][ct * 16 + l16] = qq; }
    }
    __syncthreads();
    if (t < 128) {
        atomicAdd(&colsum[t], cp[0][t] + cp[1][t] + cp[2][t] + cp[3][t]);
        atomicAdd(&colsumsq[t], cq[0][t] + cq[1][t] + cq[2][t] + cq[3][t]);
    }
}

__global__ __launch_bounds__(256) void k_final(const uint* __restrict__ hb,
                                               const float* __restrict__ x,
                                               const float* __restrict__ gamma,
                                               const float* __restrict__ beta,
                                               const float* __restrict__ colsum,
                                               const float* __restrict__ colsumsq,
                                               float* __restrict__ out, int out_size) {
    int gid = blockIdx.x * 256 + threadIdx.x;     // float4 index over ND/4
    int c4 = (gid & 31) * 4;
    uint2 hv = ((const uint2*)hb)[gid];
    const float4 xv = ((const float4*)x)[gid];
    float hval[4] = { b2f(hv.x & 0xFFFFu), b2f(hv.x >> 16),
                      b2f(hv.y & 0xFFFFu), b2f(hv.y >> 16) };
    const float invN = 1.0f / NN;
    float4 o;
    float res[4];
#pragma unroll
    for (int j = 0; j < 4; ++j) {
        float m = colsum[c4 + j] * invN;
        float var = colsumsq[c4 + j] * invN - m * m;
        float inv = rsqrtf(var + BN_EPS);
        float val = (hval[j] - m) * inv * gamma[c4 + j] + beta[c4 + j];
        res[j] = fmaxf(val, 0.f);
    }
    o.x = res[0] + xv.x; o.y = res[1] + xv.y;
    o.z = res[2] + xv.z; o.w = res[3] + xv.w;
    ((float4*)out)[gid] = o;
    if (gid == 0 && out_size > ND) out[ND] = 0.0f;
}

extern "C" void kernel_launch(void* const* d_in, const int* in_sizes, int n_in,
                              void* d_out, int out_size, void* d_ws, size_t ws_size,
                              hipStream_t stream) {
    const float* x     = (const float*)d_in[0];
    const int*   ei    = (const int*)d_in[1];
    const float* W     = (const float*)d_in[2];
    const float* gamma = (const float*)d_in[4];
    const float* beta  = (const float*)d_in[5];
    float* ws = (float*)d_ws;
    float* out = (float*)d_out;

    uint*   hb       = (uint*)ws;
    uint*   xb       = hb + ND / 2;
    uint*   aggb     = xb + ND / 2;
    float*  colsum   = (float*)(aggb + ND / 2);
    float*  colsumsq = colsum + 128;
    int*    cnt      = (int*)(colsumsq + 128);
    int*    ptr0     = cnt + NN;
    int*    pcur     = ptr0 + NN;
    float*  dinv     = (float*)(pcur + NN);
    int*    bsum     = (int*)(dinv + NN);
    uint2*  edata    = (uint2*)(bsum + 136);      // 8-byte aligned

    int E = in_sizes[1] / 2;
    uint* wb = (uint*)(edata + E);

    hipMemsetAsync(colsum, 0, (size_t)(256 + NN) * 4, stream);
    k_hist<<<(E + 255) / 256, 256, 0, stream>>>(ei, cnt, E);
    k_scan1<<<EE_SCAN_NB, 256, 0, stream>>>(cnt, bsum);
    k_scan2<<<1, 128, 0, stream>>>(bsum);
    k_scan3<<<EE_SCAN_NB, 256, 0, stream>>>(cnt, bsum, ptr0, pcur, dinv);
    k_cvt<<<(ND / 8 + 2048 + 255) / 256, 256, 0, stream>>>(x, xb, W, wb);
    k_scatter<<<(E + 255) / 256, 256, 0, stream>>>(ei, dinv, pcur, edata, E);
    k_gather<<<NN / 4, 256, 0, stream>>>(xb, edata, ptr0, cnt, dinv, aggb);
    k_gemm<<<(NN + 63) / 64, 256, 0, stream>>>((const ushort*)aggb, (const ushort*)wb,
                                               (ushort*)hb, colsum, colsumsq);
    k_final<<<ND / (256 * 4), 256, 0, stream>>>(hb, x, gamma, beta,
                                                colsum, colsumsq, out, out_size);
}

// Round 5
// 291.395 us; speedup vs baseline: 5.6794x; 1.0552x over previous
//
#include <hip/hip_runtime.h>
#include <cstddef>

#define NN 100000
#define DD 128
#define ND (NN * DD)
#define EE_SCAN_NB 98          // ceil(100000/1024)
#define BN_EPS 1e-5f
#define LDA 136                // LDS A row stride in bf16 elems (272 B, 16B-aligned)
#define NREP 64                // stats-accumulator replicas

typedef __bf16 bf16_t;
typedef bf16_t bf16x8 __attribute__((ext_vector_type(8)));
typedef float f32x4 __attribute__((ext_vector_type(4)));
typedef unsigned int uint;
typedef unsigned short ushort;

// ws 4-byte-slot layout:
//   [0, ND/2)            hb   (bf16 h, [NN][128])
//   [ND/2, ND)           xb   (bf16 x)
//   [ND, 3ND/2)          aggb (bf16 S*x)
//   base3 = 3ND/2:
//   [base3, +8192)       csr  (colsum replicas [64][128], zeroed)
//   [+8192, +8192)       cqr  (colsumsq replicas, zeroed)
//   [+16384, +NN)        cnt  (int, zeroed)   <- memset covers base3 .. +16384+NN
//   then: colsum[128], colsumsq[128], ptr0[NN], pcur[NN], dinv[NN],
//         bsum[136], srow[E], wb[4096 uints]

__device__ __forceinline__ ushort f2b(float f) {
    uint u = __builtin_bit_cast(uint, f);
    u += 0x7FFFu + ((u >> 16) & 1u);          // RNE
    return (ushort)(u >> 16);
}
__device__ __forceinline__ float b2f(uint s) {
    return __builtin_bit_cast(float, s << 16);
}

// int64 edge_index => high word of every entry is 0 (ids < 100000).
__device__ __forceinline__ int detect_i64(const int* __restrict__ ei) {
    __shared__ int sflag;
    int t = threadIdx.x;
    if (t < 64) {
        int hi = ei[2 * t + 1];
        unsigned long long b = __ballot(hi == 0);
        if (t == 0) sflag = (b == ~0ull) ? 1 : 0;
    }
    __syncthreads();
    return sflag;
}

// dual-role: blocks [0, nbh) histogram cols; rest pack x and W to bf16
__global__ __launch_bounds__(256) void k_prep(const int* __restrict__ ei,
                                              int* __restrict__ cnt, int E, int nbh,
                                              const float* __restrict__ x,
                                              uint* __restrict__ xb,
                                              const float* __restrict__ W,
                                              uint* __restrict__ wb) {
    if ((int)blockIdx.x < nbh) {
        int f = detect_i64(ei);
        int e = blockIdx.x * 256 + threadIdx.x;
        if (e >= E) return;
        int c = f ? ei[2 * (E + e)] : ei[E + e];
        atomicAdd(&cnt[c], 1);
        return;
    }
    int i = (blockIdx.x - nbh) * 256 + threadIdx.x;
    const float* src;
    uint* dst;
    int j;
    if (i < ND / 8) { src = x; dst = xb; j = i; }
    else { j = i - ND / 8; if (j >= (DD * DD) / 8) return; src = W; dst = wb; }
    const float4* s4 = (const float4*)src;
    float4 a = s4[2 * j], b = s4[2 * j + 1];
    uint4 o;
    o.x = (uint)f2b(a.x) | ((uint)f2b(a.y) << 16);
    o.y = (uint)f2b(a.z) | ((uint)f2b(a.w) << 16);
    o.z = (uint)f2b(b.x) | ((uint)f2b(b.y) << 16);
    o.w = (uint)f2b(b.z) | ((uint)f2b(b.w) << 16);
    ((uint4*)dst)[j] = o;
}

__global__ __launch_bounds__(256) void k_scan1(const int* __restrict__ cnt,
                                               int* __restrict__ bsum) {
    int t = threadIdx.x;
    int base = blockIdx.x * 1024 + t * 4;
    int s = 0;
#pragma unroll
    for (int i = 0; i < 4; ++i) {
        int idx = base + i;
        if (idx < NN) s += cnt[idx];
    }
    __shared__ int ls[256];
    ls[t] = s;
    __syncthreads();
    for (int o = 128; o > 0; o >>= 1) {
        if (t < o) ls[t] += ls[t + o];
        __syncthreads();
    }
    if (t == 0) bsum[blockIdx.x] = ls[0];
}

__global__ void k_scan2(int* __restrict__ bsum) {
    int t = threadIdx.x;
    __shared__ int ls[EE_SCAN_NB];
    if (t < EE_SCAN_NB) ls[t] = bsum[t];
    __syncthreads();
    if (t == 0) {
        int run = 0;
        for (int i = 0; i < EE_SCAN_NB; ++i) { int v = ls[i]; ls[i] = run; run += v; }
    }
    __syncthreads();
    if (t < EE_SCAN_NB) bsum[t] = ls[t];
}

__global__ __launch_bounds__(256) void k_scan3(const int* __restrict__ cnt,
                                               const int* __restrict__ bsum,
                                               int* __restrict__ ptr0,
                                               int* __restrict__ pcur,
                                               float* __restrict__ dinv) {
    int t = threadIdx.x;
    int base = blockIdx.x * 1024 + t * 4;
    int c[4];
    int lsum = 0;
#pragma unroll
    for (int i = 0; i < 4; ++i) {
        int idx = base + i;
        c[i] = (idx < NN) ? cnt[idx] : 0;
        lsum += c[i];
    }
    __shared__ int ls[256];
    ls[t] = lsum;
    __syncthreads();
    for (int o = 1; o < 256; o <<= 1) {
        int v = (t >= o) ? ls[t - o] : 0;
        __syncthreads();
        ls[t] += v;
        __syncthreads();
    }
    int run = ls[t] - lsum + bsum[blockIdx.x];
#pragma unroll
    for (int i = 0; i < 4; ++i) {
        int idx = base + i;
        if (idx < NN) {
            ptr0[idx] = run;
            pcur[idx] = run;
            dinv[idx] = c[i] > 0 ? rsqrtf((float)c[i]) : 0.f;
        }
        run += c[i];
    }
}

__global__ __launch_bounds__(256) void k_scatter(const int* __restrict__ ei,
                                                 int* __restrict__ pcur,
                                                 int* __restrict__ srow, int E) {
    int f = detect_i64(ei);
    int e = blockIdx.x * 256 + threadIdx.x;
    if (e >= E) return;
    int r, c;
    if (f) { r = ei[2 * e]; c = ei[2 * (E + e)]; }
    else   { r = ei[e];     c = ei[E + e]; }
    int p = atomicAdd(&pcur[c], 1);
    srow[p] = r;
}

// one wave per node. Lane l loads edge s+l's (src, dinv[src]) itself, then
// broadcast via shfl; xb row loads issued 4-deep.
__global__ __launch_bounds__(256) void k_gather(const uint* __restrict__ xb,
                                                const int* __restrict__ srow,
                                                const int* __restrict__ ptr0,
                                                const int* __restrict__ cnt,
                                                const float* __restrict__ dinv,
                                                uint* __restrict__ aggb) {
    int n = blockIdx.x * 4 + (threadIdx.x >> 6);
    int lane = threadIdx.x & 63;
    int s = ptr0[n];
    int k = cnt[n];
    float dc = dinv[n];
    float ax = 0.f, ay = 0.f;
    for (int base = 0; base < k; base += 64) {
        int m = min(k - base, 64);
        int rj = 0; float wj = 0.f;
        if (lane < m) { rj = srow[s + base + lane]; wj = dinv[rj]; }
        int j = 0;
        for (; j + 4 <= m; j += 4) {
            int r0 = __shfl(rj, j);     float w0 = __shfl(wj, j);
            int r1 = __shfl(rj, j + 1); float w1 = __shfl(wj, j + 1);
            int r2 = __shfl(rj, j + 2); float w2 = __shfl(wj, j + 2);
            int r3 = __shfl(rj, j + 3); float w3 = __shfl(wj, j + 3);
            uint v0 = xb[(size_t)r0 * 64 + lane];
            uint v1 = xb[(size_t)r1 * 64 + lane];
            uint v2 = xb[(size_t)r2 * 64 + lane];
            uint v3 = xb[(size_t)r3 * 64 + lane];
            ax = fmaf(w0, b2f(v0 & 0xFFFFu), ax); ay = fmaf(w0, b2f(v0 >> 16), ay);
            ax = fmaf(w1, b2f(v1 & 0xFFFFu), ax); ay = fmaf(w1, b2f(v1 >> 16), ay);
            ax = fmaf(w2, b2f(v2 & 0xFFFFu), ax); ay = fmaf(w2, b2f(v2 >> 16), ay);
            ax = fmaf(w3, b2f(v3 & 0xFFFFu), ax); ay = fmaf(w3, b2f(v3 >> 16), ay);
        }
        for (; j < m; ++j) {
            int r = __shfl(rj, j);
            float w = __shfl(wj, j);
            uint v = xb[(size_t)r * 64 + lane];
            ax = fmaf(w, b2f(v & 0xFFFFu), ax);
            ay = fmaf(w, b2f(v >> 16), ay);
        }
    }
    aggb[(size_t)n * 64 + lane] = (uint)f2b(dc * ax) | ((uint)f2b(dc * ay) << 16);
}

// hb = aggb @ W^T via MFMA bf16 + fused column stats into replicated banks.
__global__ __launch_bounds__(256, 2) void k_gemm(const ushort* __restrict__ aggb,
                                                 const ushort* __restrict__ wb,
                                                 ushort* __restrict__ hb,
                                                 float* __restrict__ csr,
                                                 float* __restrict__ cqr) {
    __shared__ ushort sA[64 * LDA];           // 17.4 KB
    __shared__ float cp[4][128], cq[4][128];  // 4 KB
    int t = threadIdx.x;
    int wave = t >> 6, lane = t & 63;
    int quad = lane >> 4, l16 = lane & 15;
    size_t rowbase = (size_t)blockIdx.x * 64;

    bf16x8 Bf[8][4];
#pragma unroll
    for (int ct = 0; ct < 8; ++ct)
#pragma unroll
        for (int ks = 0; ks < 4; ++ks) {
            const uint4* p =
                (const uint4*)(wb + (size_t)(ct * 16 + l16) * 128 + ks * 32 + quad * 8);
            Bf[ct][ks] = __builtin_bit_cast(bf16x8, *p);
        }

    // stage A (OOB rows -> zeros so fused stats stay exact)
#pragma unroll
    for (int i = 0; i < 4; ++i) {
        int c = t + i * 256;
        int r = c >> 4, pos = c & 15;
        size_t gr = rowbase + r;
        uint4 v = {0u, 0u, 0u, 0u};
        if (gr < NN) v = *(const uint4*)(aggb + gr * 128 + pos * 8);
        *(uint4*)(sA + r * LDA + pos * 8) = v;
    }
    __syncthreads();

    bf16x8 Af[4];
#pragma unroll
    for (int ks = 0; ks < 4; ++ks)
        Af[ks] = __builtin_bit_cast(
            bf16x8, *(const uint4*)(sA + (wave * 16 + l16) * LDA + ks * 32 + quad * 8));

    f32x4 acc[8];
#pragma unroll
    for (int ct = 0; ct < 8; ++ct) {
        acc[ct] = (f32x4){0.f, 0.f, 0.f, 0.f};
#pragma unroll
        for (int ks = 0; ks < 4; ++ks)
            acc[ct] = __builtin_amdgcn_mfma_f32_16x16x32_bf16(Af[ks], Bf[ct][ks],
                                                              acc[ct], 0, 0, 0);
    }

#pragma unroll
    for (int ct = 0; ct < 8; ++ct) {
        float ss = 0.f, qq = 0.f;
#pragma unroll
        for (int r = 0; r < 4; ++r) {
            float v = acc[ct][r];
            ss += v; qq += v * v;
            size_t row = rowbase + wave * 16 + quad * 4 + r;
            if (row < NN) hb[row * 128 + ct * 16 + l16] = f2b(v);
        }
        ss += __shfl_xor(ss, 16); ss += __shfl_xor(ss, 32);
        qq += __shfl_xor(qq, 16); qq += __shfl_xor(qq, 32);
        if (quad == 0) { cp[wave][ct * 16 + l16] = ss; cq[wave][ct * 16 + l16] = qq; }
    }
    __syncthreads();
    if (t < 128) {
        int rep = (blockIdx.x & (NREP - 1)) * 128 + t;
        atomicAdd(&csr[rep], cp[0][t] + cp[1][t] + cp[2][t] + cp[3][t]);
        atomicAdd(&cqr[rep], cq[0][t] + cq[1][t] + cq[2][t] + cq[3][t]);
    }
}

// fold the 64 replicas
__global__ void k_red(const float* __restrict__ csr, const float* __restrict__ cqr,
                      float* __restrict__ colsum, float* __restrict__ colsumsq) {
    int t = threadIdx.x;          // 256
    if (t < 128) {
        float s = 0.f;
        for (int i = 0; i < NREP; ++i) s += csr[i * 128 + t];
        colsum[t] = s;
    } else {
        int c = t - 128;
        float s = 0.f;
        for (int i = 0; i < NREP; ++i) s += cqr[i * 128 + c];
        colsumsq[c] = s;
    }
}

__global__ __launch_bounds__(256) void k_final(const uint* __restrict__ hb,
                                               const uint* __restrict__ xb,
                                               const float* __restrict__ gamma,
                                               const float* __restrict__ beta,
                                               const float* __restrict__ colsum,
                                               const float* __restrict__ colsumsq,
                                               float* __restrict__ out, int out_size) {
    int gid = blockIdx.x * 256 + threadIdx.x;     // 4-col group index over ND/4
    int c4 = (gid & 31) * 4;
    uint2 hv = ((const uint2*)hb)[gid];
    uint2 xv = ((const uint2*)xb)[gid];
    float hval[4] = { b2f(hv.x & 0xFFFFu), b2f(hv.x >> 16),
                      b2f(hv.y & 0xFFFFu), b2f(hv.y >> 16) };
    float xval[4] = { b2f(xv.x & 0xFFFFu), b2f(xv.x >> 16),
                      b2f(xv.y & 0xFFFFu), b2f(xv.y >> 16) };
    const float invN = 1.0f / NN;
    float4 o;
    float res[4];
#pragma unroll
    for (int j = 0; j < 4; ++j) {
        float m = colsum[c4 + j] * invN;
        float var = colsumsq[c4 + j] * invN - m * m;
        float inv = rsqrtf(var + BN_EPS);
        float val = (hval[j] - m) * inv * gamma[c4 + j] + beta[c4 + j];
        res[j] = fmaxf(val, 0.f) + xval[j];
    }
    o.x = res[0]; o.y = res[1]; o.z = res[2]; o.w = res[3];
    ((float4*)out)[gid] = o;
    if (gid == 0 && out_size > ND) out[ND] = 0.0f;
}

extern "C" void kernel_launch(void* const* d_in, const int* in_sizes, int n_in,
                              void* d_out, int out_size, void* d_ws, size_t ws_size,
                              hipStream_t stream) {
    const float* x     = (const float*)d_in[0];
    const int*   ei    = (const int*)d_in[1];
    const float* W     = (const float*)d_in[2];
    const float* gamma = (const float*)d_in[4];
    const float* beta  = (const float*)d_in[5];
    float* ws = (float*)d_ws;
    float* out = (float*)d_out;

    uint*   hb       = (uint*)ws;
    uint*   xb       = hb + ND / 2;
    uint*   aggb     = xb + ND / 2;
    float*  csr      = (float*)(aggb + ND / 2);        // 64*128
    float*  cqr      = csr + NREP * 128;               // 64*128
    int*    cnt      = (int*)(cqr + NREP * 128);
    float*  colsum   = (float*)(cnt + NN);
    float*  colsumsq = colsum + 128;
    int*    ptr0     = (int*)(colsumsq + 128);
    int*    pcur     = ptr0 + NN;
    float*  dinv     = (float*)(pcur + NN);
    int*    bsum     = (int*)(dinv + NN);
    int*    srow     = bsum + 136;

    int E = in_sizes[1] / 2;
    uint* wb = (uint*)(srow + E);

    int nbh = (E + 255) / 256;
    int nbc = (ND / 8 + (DD * DD) / 8 + 255) / 256;

    // zero stat replicas + cnt
    hipMemsetAsync(csr, 0, (size_t)(2 * NREP * 128 + NN) * 4, stream);
    k_prep<<<nbh + nbc, 256, 0, stream>>>(ei, cnt, E, nbh, x, xb, W, wb);
    k_scan1<<<EE_SCAN_NB, 256, 0, stream>>>(cnt, bsum);
    k_scan2<<<1, 128, 0, stream>>>(bsum);
    k_scan3<<<EE_SCAN_NB, 256, 0, stream>>>(cnt, bsum, ptr0, pcur, dinv);
    k_scatter<<<nbh, 256, 0, stream>>>(ei, pcur, srow, E);
    k_gather<<<NN / 4, 256, 0, stream>>>(xb, srow, ptr0, cnt, dinv, aggb);
    k_gemm<<<(NN + 63) / 64, 256, 0, stream>>>((const ushort*)aggb, (const ushort*)wb,
                                               (ushort*)hb, csr, cqr);
    k_red<<<1, 256, 0, stream>>>(csr, cqr, colsum, colsumsq);
    k_final<<<ND / (256 * 4), 256, 0, stream>>>(hb, xb, gamma, beta,
                                                colsum, colsumsq, out, out_size);
}